// Round 3
// baseline (336.499 us; speedup 1.0000x reference)
//
#include <hip/hip_runtime.h>
#include <math.h>

#define H128 128
#define NF 512  // A*C*H = 2*2*128 features per node
typedef unsigned short u16;
typedef __attribute__((ext_vector_type(8))) short short8;   // 8 bf16 = 4 VGPRs
typedef __attribute__((ext_vector_type(4))) float floatx4;  // mfma accumulator

// fp32 -> bf16 round-to-nearest-even
__device__ inline u16 f2bf(float f) {
  union { float f; unsigned u; } x; x.f = f;
  unsigned r = x.u + 0x7FFFu + ((x.u >> 16) & 1u);
  return (u16)(r >> 16);
}
// accumulate 8 bf16 (packed in uint4) into fp32 acc
__device__ inline void addbf8(float* a, uint4 u) {
  a[0] += __uint_as_float(u.x << 16);
  a[1] += __uint_as_float(u.x & 0xFFFF0000u);
  a[2] += __uint_as_float(u.y << 16);
  a[3] += __uint_as_float(u.y & 0xFFFF0000u);
  a[4] += __uint_as_float(u.z << 16);
  a[5] += __uint_as_float(u.z & 0xFFFF0000u);
  a[6] += __uint_as_float(u.w << 16);
  a[7] += __uint_as_float(u.w & 0xFFFF0000u);
}

// ---------------- fused degree count: one thread handles src+dst of one edge ----------------
__global__ void k_count2(const int* __restrict__ e0s, const int* __restrict__ e0d,
                         const int* __restrict__ e1s, const int* __restrict__ e1d,
                         int E0, int E1,
                         int* __restrict__ c_s0, int* __restrict__ c_d0,
                         int* __restrict__ c_s1, int* __restrict__ c_d1) {
  int i = blockIdx.x * 256 + threadIdx.x;
  if (i < E0) {
    atomicAdd(&c_s0[e0s[i]], 1);
    atomicAdd(&c_d0[e0d[i]], 1);
    return;
  }
  i -= E0;
  if (i < E1) {
    atomicAdd(&c_s1[e1s[i]], 1);
    atomicAdd(&c_d1[e1d[i]], 1);
  }
}

// ---------------- fused prep: blocks 0-1 scan, blocks 2-3 wfrag, blocks 4.. norm ----------------
// norm writes to SEPARATE normf buffer (cnt stays int) -> no race with scan readers.
// wfrag: wfrag[(ct*4+kc)*64 + lane] = 8 bf16: W[kc*32 + (lane>>4)*8 + j][ct*16 + (lane&15)]
__global__ __launch_bounds__(1024) void k_prep(
    const int* __restrict__ cnt, int NCNT, float* __restrict__ normf,
    const int* __restrict__ degA, int nA, int* __restrict__ offA, int* __restrict__ curA,
    const int* __restrict__ degB, int nB, int* __restrict__ offB, int* __restrict__ curB,
    const float* __restrict__ W, uint4* __restrict__ wfrag) {
  __shared__ int wsum[16];
  const int b = blockIdx.x;
  const int tid = threadIdx.x;
  if (b < 2) {
    // single-pass exclusive scan (1024 thr, 2 barriers)
    const int* deg = b ? degB : degA;
    int n = b ? nB : nA;
    int* off = b ? offB : offA;
    int* cur = b ? curB : curA;
    const int lane = tid & 63;
    const int wv = tid >> 6;
    const int per = (n + 1023) >> 10;
    const int base = tid * per;
    int cntk = n - base;
    if (cntk < 0) cntk = 0;
    if (cntk > per) cntk = per;
    int sum = 0;
    for (int i = 0; i < cntk; ++i) sum += deg[base + i];
    int x = sum;
    #pragma unroll
    for (int d2 = 1; d2 < 64; d2 <<= 1) {
      int y = __shfl_up(x, (unsigned)d2, 64);
      if (lane >= d2) x += y;
    }
    if (lane == 63) wsum[wv] = x;
    __syncthreads();
    if (wv == 0 && lane < 16) {
      int w = wsum[lane];
      #pragma unroll
      for (int d2 = 1; d2 < 16; d2 <<= 1) {
        int y = __shfl_up(w, (unsigned)d2, 64);
        if (lane >= d2) w += y;
      }
      wsum[lane] = w;
    }
    __syncthreads();
    int tbase = x - sum + (wv ? wsum[wv - 1] : 0);
    int running = tbase;
    for (int i = 0; i < cntk; ++i) {
      off[base + i] = running;
      cur[base + i] = running;
      running += deg[base + i];
    }
    if (tid == 1023) off[n] = wsum[15];
    return;
  }
  if (b < 4) {
    // W fp32 [128][128] -> bf16 B-fragment order (2048 entries)
    int t = (b - 2) * 1024 + tid;
    if (t < 2048) {
      int lane = t & 63;
      int pair = t >> 6;  // ct*4 + kc
      int ct = pair >> 2, kc = pair & 3;
      int quad = lane >> 4, r = lane & 15;
      const float* src = W + (size_t)(kc * 32 + quad * 8) * 128 + ct * 16 + r;
      union { u16 v[8]; uint4 u; } pk;
      #pragma unroll
      for (int j = 0; j < 8; ++j) pk.v[j] = f2bf(src[(size_t)j * 128]);
      wfrag[t] = pk.u;
    }
    return;
  }
  // degree -> float norm = 1/sqrt(max(d,1))
  int i = (b - 4) * 1024 + tid;
  if (i < NCNT) {
    int d = cnt[i];
    float dv = (d < 1) ? 1.0f : (float)d;
    normf[i] = 1.0f / sqrtf(dv);
  }
}

// ---------------- fused transpose-in (wide-row tiles) + CSR scatter ----------------
// Blocks [0, SB): scatter (4 edges/thread, atomic CSR fill).
// Blocks [SB, ...): tile = 256 nodes x 32 h for one ac group.
// KEY CHANGE (r3): each wave's global load is ONE CONTIGUOUS 1 KB h-row segment
// (64 lanes x float4 along n) -- the exact pattern of the 6.3 TB/s BW microbench.
// Previous 64-node tiles issued 4x256B segments 400KB apart per wave-load and all
// variants capped at ~2 TB/s regardless of occupancy/MLP (r1/r2 evidence).
// LDS [nl][cs] fp32 32 KB, cs = (hl + nl + (nl>>5)) & 31:
//   phase-1 writes: bank = hl + 4p + q (lane=8q+p) -> exact 2-way = free (m136).
//   phase-2 reads: same form -> 2-way, free.
// Phase-2 stores: 8 lanes = one node's 64B h-chunk segment (line-sized).
__global__ __launch_bounds__(512) void k_tin_scatter(
    const float* __restrict__ in, const float* __restrict__ norm,
    u16* __restrict__ xp, int N, int SB,
    const int* __restrict__ e0s, const int* __restrict__ e0d,
    const int* __restrict__ e1s, const int* __restrict__ e1d,
    int E0, int E1,
    int* __restrict__ cur0, int* __restrict__ csr0,
    int* __restrict__ cur1, int* __restrict__ csr1) {
  __shared__ float tile[256 * 32];  // 32 KB
  const int bid = blockIdx.x;
  const int tid = threadIdx.x;
  if (bid < SB) {
    #pragma unroll
    for (int k = 0; k < 4; ++k) {
      int i = (bid * 4 + k) * 512 + tid;
      if (i < E0) {
        int p = atomicAdd(&cur0[e0d[i]], 1);
        csr0[p] = e0s[i];
      } else {
        i -= E0;
        if (i < E1) {
          int p = atomicAdd(&cur1[e1d[i]], 1);
          csr1[p] = e1s[i];
        }
      }
    }
    return;
  }
  const int tb = bid - SB;
  const int hc = tb & 3;          // h-chunk (32 h's)
  const int ac = (tb >> 2) & 3;   // a*2+c
  const int ti = tb >> 4;         // 256-node tile
  const int n0 = ti << 8;
  const int h0 = hc << 5;
  const int a = ac >> 1, c = ac & 1;
  const float* base = in + ((size_t)a * 256 + (size_t)h0 * 2 + c) * (size_t)N;
  const int lane = tid & 63;
  const int w = tid >> 6;
  // ---- phase 1: 4 wave-contiguous 1KB row loads, swizzled LDS write ----
  const int gnl = n0 + (lane << 2);
  float4 v[4];
  #pragma unroll
  for (int i = 0; i < 4; ++i) {
    const int hl = i * 8 + w;
    v[i] = make_float4(0.f, 0.f, 0.f, 0.f);
    if (gnl < N) v[i] = *(const float4*)(base + (size_t)hl * 2 * N + gnl);
  }
  #pragma unroll
  for (int i = 0; i < 4; ++i) {
    const int hl = i * 8 + w;
    float vv[4] = {v[i].x, v[i].y, v[i].z, v[i].w};
    #pragma unroll
    for (int j = 0; j < 4; ++j) {
      const int nl = (lane << 2) + j;
      const int cs = (hl + nl + (nl >> 5)) & 31;
      tile[nl * 32 + cs] = vv[j];
    }
  }
  __syncthreads();
  // ---- phase 2: per thread one node x 4 h -> ushort4 (8B) store ----
  #pragma unroll
  for (int i = 0; i < 4; ++i) {
    const int nl = i * 64 + (tid >> 3);
    const int gn = n0 + nl;
    if (gn < N) {
      const int hq = tid & 7;
      const float s = norm[gn];
      const int rb = nl * 32;
      const int ofs = nl + (nl >> 5);
      float f0 = tile[rb + ((4 * hq + 0 + ofs) & 31)];
      float f1 = tile[rb + ((4 * hq + 1 + ofs) & 31)];
      float f2 = tile[rb + ((4 * hq + 2 + ofs) & 31)];
      float f3 = tile[rb + ((4 * hq + 3 + ofs) & 31)];
      ushort4 o;
      o.x = f2bf(f0 * s); o.y = f2bf(f1 * s);
      o.z = f2bf(f2 * s); o.w = f2bf(f3 * s);
      *(ushort4*)(xp + (size_t)gn * NF + ac * H128 + h0 + hq * 4) = o;
    }
  }
}

// ---------------- fused aggregate + MFMA GEMM ----------------
// Block = 4 waves = 16 dst nodes. Wave w gathers nodes d0+w*4..+3 (full 512-feat
// row across 64 lanes, 8-deep unrolled gather), scales by norm_dst, writes bf16
// row to LDS atile (pad 520 -> b128 reads ~conflict-light). One barrier, then
// wave w computes the ac=w GEMM: out[16,128] = relu(A[16,128] @ W + b) (*scale).
// MODE 0: out bf16 [n][512], per-node scale (next layer's src norm).
// MODE 1: out fp32 written DIRECTLY transposed to [A,H,C,Nout] (final output;
//         node index = quad*4+reg -> 4 consecutive n = one float4 per thread).
template <int MODE>
__global__ __launch_bounds__(256) void k_agg_gemm(
    const u16* __restrict__ xp, const int* __restrict__ csr,
    const int* __restrict__ off, const float* __restrict__ norm_dst,
    const uint4* __restrict__ wfrag, const float* __restrict__ bias,
    const float* __restrict__ scale, void* __restrict__ outv, int Nout) {
  __shared__ uint4 wb[2048];      // 32 KB B-frags
  __shared__ u16 atile[16][520];  // 16.25 KB, rows 1040 B (16B aligned)
  const int tid = threadIdx.x;
  #pragma unroll
  for (int i = 0; i < 8; ++i) wb[i * 256 + tid] = wfrag[i * 256 + tid];
  const int wave = tid >> 6;
  const int lane = tid & 63;
  const int d0 = blockIdx.x << 4;
  // ---- gather phase ----
  const uint4* xpl = (const uint4*)xp + lane;  // lane's 16B slot; row stride 64 uint4
  #pragma unroll
  for (int i = 0; i < 4; ++i) {
    const int m = wave * 4 + i;
    const int d = d0 + m;
    const int s = off[d], e = off[d + 1];  // wave-uniform
    float acc[8];
    #pragma unroll
    for (int k = 0; k < 8; ++k) acc[k] = 0.f;
    int j = s;
    for (; j + 8 <= e; j += 8) {
      uint4 u[8];
      #pragma unroll
      for (int k = 0; k < 8; ++k) u[k] = xpl[(size_t)csr[j + k] * 64];
      #pragma unroll
      for (int k = 0; k < 8; ++k) addbf8(acc, u[k]);
    }
    for (; j < e; ++j) addbf8(acc, xpl[(size_t)csr[j] * 64]);
    float nd = norm_dst[d];
    union { u16 v[8]; uint4 u; } pk;
    #pragma unroll
    for (int k = 0; k < 8; ++k) pk.v[k] = f2bf(acc[k] * nd);
    *(uint4*)&atile[m][lane * 8] = pk.u;  // contiguous 1KB per wave
  }
  __syncthreads();
  // ---- GEMM phase: wave handles ac = wave ----
  const int quad = lane >> 4;
  const int r = lane & 15;
  short8 a[4];
  #pragma unroll
  for (int kc = 0; kc < 4; ++kc)
    a[kc] = *(const short8*)&atile[r][wave * 128 + kc * 32 + quad * 8];
  floatx4 acc[8];
  #pragma unroll
  for (int ct = 0; ct < 8; ++ct) acc[ct] = (floatx4){0.f, 0.f, 0.f, 0.f};
  #pragma unroll
  for (int kc = 0; kc < 4; ++kc) {
    #pragma unroll
    for (int ct = 0; ct < 8; ++ct) {
      short8 b = *(const short8*)&wb[(ct * 4 + kc) * 64 + lane];
      acc[ct] = __builtin_amdgcn_mfma_f32_16x16x32_bf16(a[kc], b, acc[ct], 0, 0, 0);
    }
  }
  // ---- epilogue: C/D row = quad*4+reg = node, col = ct*16+r = feature-within-ac ----
  if (MODE == 0) {
    float sc[4];
    #pragma unroll
    for (int reg = 0; reg < 4; ++reg) sc[reg] = scale[d0 + quad * 4 + reg];
    #pragma unroll
    for (int ct = 0; ct < 8; ++ct) {
      float bcol = bias[ct * 16 + r];
      #pragma unroll
      for (int reg = 0; reg < 4; ++reg) {
        float v = acc[ct][reg] + bcol;
        v = (v > 0.f ? v : 0.f) * sc[reg];
        ((u16*)outv)[(size_t)(d0 + quad * 4 + reg) * NF + wave * H128 + ct * 16 + r] = f2bf(v);
      }
    }
  } else {
    // out[a][h][c][n]: a=wave>>1, c=wave&1, h=ct*16+r, n=d0+quad*4+{0..3}
    const int aa = wave >> 1, cc = wave & 1;
    #pragma unroll
    for (int ct = 0; ct < 8; ++ct) {
      float bcol = bias[ct * 16 + r];
      float4 o;
      float v0 = acc[ct][0] + bcol; o.x = v0 > 0.f ? v0 : 0.f;
      float v1 = acc[ct][1] + bcol; o.y = v1 > 0.f ? v1 : 0.f;
      float v2 = acc[ct][2] + bcol; o.z = v2 > 0.f ? v2 : 0.f;
      float v3 = acc[ct][3] + bcol; o.w = v3 > 0.f ? v3 : 0.f;
      float* dst = (float*)outv +
          ((size_t)aa * 256 + (size_t)(ct * 16 + r) * 2 + cc) * (size_t)Nout +
          d0 + quad * 4;
      *(float4*)dst = o;
    }
  }
}

extern "C" void kernel_launch(void* const* d_in, const int* in_sizes, int n_in,
                              void* d_out, int out_size, void* d_ws, size_t ws_size,
                              hipStream_t stream) {
  const float* in_feat = (const float*)d_in[0];
  const float* W       = (const float*)d_in[1];
  const float* bias    = (const float*)d_in[2];
  const int* e0_src    = (const int*)d_in[3];
  const int* e0_dst    = (const int*)d_in[4];
  const int* e1_src    = (const int*)d_in[5];
  const int* e1_dst    = (const int*)d_in[6];
  const int N_DST0 = 20000;
  const int N_DST1 = 4096;
  const int N_SRC0 = in_sizes[0] / NF;  // 50000
  const int E0 = in_sizes[3];           // 320000
  const int E1 = in_sizes[5];           // 65536

  // ---- workspace layout (fully disjoint) ----
  u16* xp = (u16*)d_ws;                  // bf16 [N_SRC0][512] = 51.2 MB
  u16* h0 = xp + (size_t)N_SRC0 * NF;    // bf16 [N_DST0][512] = 20.5 MB
  int* ibase    = (int*)(h0 + (size_t)N_DST0 * NF);
  int* cnt_src0 = ibase;
  int* cnt_dst0 = cnt_src0 + N_SRC0;
  int* cnt_src1 = cnt_dst0 + N_DST0;
  int* cnt_dst1 = cnt_src1 + N_DST0;
  int* off0 = cnt_dst1 + N_DST1;
  int* cur0 = off0 + N_DST0 + 1;
  int* csr0 = cur0 + N_DST0;
  int* off1 = csr0 + E0;
  int* cur1 = off1 + N_DST1 + 1;
  int* csr1 = cur1 + N_DST1;
  uint4* wfrag = (uint4*)(((uintptr_t)(csr1 + E1) + 15) & ~(uintptr_t)15);  // 32 KB
  float* normf = (float*)(wfrag + 2048);  // float norms, mirrors cnt layout
  float* normf_src0 = normf;
  float* normf_dst0 = normf_src0 + N_SRC0;
  float* normf_src1 = normf_dst0 + N_DST0;
  float* normf_dst1 = normf_src1 + N_DST0;

  const int NCNT = N_SRC0 + N_DST0 + N_DST0 + N_DST1;
  hipMemsetAsync(cnt_src0, 0, (size_t)NCNT * sizeof(int), stream);

  // degree count (1 thread = both endpoints of 1 edge)
  k_count2<<<(E0 + E1 + 255) / 256, 256, 0, stream>>>(
      e0_src, e0_dst, e1_src, e1_dst, E0, E1, cnt_src0, cnt_dst0, cnt_src1, cnt_dst1);

  // fused scan (2 blocks) + wfrag pack (2 blocks) + norm (rest)
  k_prep<<<4 + (NCNT + 1023) / 1024, 1024, 0, stream>>>(
      cnt_src0, NCNT, normf,
      cnt_dst0, N_DST0, off0, cur0,
      cnt_dst1, N_DST1, off1, cur1,
      W, wfrag);

  // fused CSR scatter + wide-row input transpose
  const int SB = (E0 + E1 + 2047) / 2048;            // 4 edges/thread
  const int ntiles = (N_SRC0 + 255) / 256;           // 256-node tiles
  const int TB = ntiles * 16;                        // x 4 ac x 4 h-chunks
  k_tin_scatter<<<SB + TB, 512, 0, stream>>>(
      in_feat, normf_src0, xp, N_SRC0, SB,
      e0_src, e0_dst, e1_src, e1_dst, E0, E1,
      cur0, csr0, cur1, csr1);

  // layer 0: fused aggregate + GEMM -> bf16 h0 (folds layer-1 src norm)
  k_agg_gemm<0><<<N_DST0 / 16, 256, 0, stream>>>(
      xp, csr0, off0, normf_dst0, wfrag, bias, normf_src1, (void*)h0, 0);

  // layer 1: fused aggregate + GEMM -> fp32 written directly transposed to d_out
  k_agg_gemm<1><<<N_DST1 / 16, 256, 0, stream>>>(
      h0, csr1, off1, normf_dst1, wfrag, bias, nullptr, d_out, N_DST1);
}

// Round 5
// 328.874 us; speedup vs baseline: 1.0232x; 1.0232x over previous
//
#include <hip/hip_runtime.h>
#include <math.h>

#define H128 128
#define NF 512  // A*C*H = 2*2*128 features per node
typedef unsigned short u16;
typedef __attribute__((ext_vector_type(8))) short short8;   // 8 bf16 = 4 VGPRs
typedef __attribute__((ext_vector_type(4))) float floatx4;  // mfma accumulator

// fp32 -> bf16 round-to-nearest-even
__device__ inline u16 f2bf(float f) {
  union { float f; unsigned u; } x; x.f = f;
  unsigned r = x.u + 0x7FFFu + ((x.u >> 16) & 1u);
  return (u16)(r >> 16);
}
// accumulate 8 bf16 (packed in uint4) into fp32 acc
__device__ inline void addbf8(float* a, uint4 u) {
  a[0] += __uint_as_float(u.x << 16);
  a[1] += __uint_as_float(u.x & 0xFFFF0000u);
  a[2] += __uint_as_float(u.y << 16);
  a[3] += __uint_as_float(u.y & 0xFFFF0000u);
  a[4] += __uint_as_float(u.z << 16);
  a[5] += __uint_as_float(u.z & 0xFFFF0000u);
  a[6] += __uint_as_float(u.w << 16);
  a[7] += __uint_as_float(u.w & 0xFFFF0000u);
}

// ---------------- fused degree count: one thread handles src+dst of one edge ----------------
__global__ void k_count2(const int* __restrict__ e0s, const int* __restrict__ e0d,
                         const int* __restrict__ e1s, const int* __restrict__ e1d,
                         int E0, int E1,
                         int* __restrict__ c_s0, int* __restrict__ c_d0,
                         int* __restrict__ c_s1, int* __restrict__ c_d1) {
  int i = blockIdx.x * 256 + threadIdx.x;
  if (i < E0) {
    atomicAdd(&c_s0[e0s[i]], 1);
    atomicAdd(&c_d0[e0d[i]], 1);
    return;
  }
  i -= E0;
  if (i < E1) {
    atomicAdd(&c_s1[e1s[i]], 1);
    atomicAdd(&c_d1[e1d[i]], 1);
  }
}

// ---------------- fused prep: blocks 0-1 scan, blocks 2-3 wfrag, blocks 4.. norm ----------------
// norm writes to SEPARATE normf buffer (cnt stays int) -> no race with scan readers.
// wfrag: wfrag[(ct*4+kc)*64 + lane] = 8 bf16: W[kc*32 + (lane>>4)*8 + j][ct*16 + (lane&15)]
__global__ __launch_bounds__(1024) void k_prep(
    const int* __restrict__ cnt, int NCNT, float* __restrict__ normf,
    const int* __restrict__ degA, int nA, int* __restrict__ offA, int* __restrict__ curA,
    const int* __restrict__ degB, int nB, int* __restrict__ offB, int* __restrict__ curB,
    const float* __restrict__ W, uint4* __restrict__ wfrag) {
  __shared__ int wsum[16];
  const int b = blockIdx.x;
  const int tid = threadIdx.x;
  if (b < 2) {
    // single-pass exclusive scan (1024 thr, 2 barriers)
    const int* deg = b ? degB : degA;
    int n = b ? nB : nA;
    int* off = b ? offB : offA;
    int* cur = b ? curB : curA;
    const int lane = tid & 63;
    const int wv = tid >> 6;
    const int per = (n + 1023) >> 10;
    const int base = tid * per;
    int cntk = n - base;
    if (cntk < 0) cntk = 0;
    if (cntk > per) cntk = per;
    int sum = 0;
    for (int i = 0; i < cntk; ++i) sum += deg[base + i];
    int x = sum;
    #pragma unroll
    for (int d2 = 1; d2 < 64; d2 <<= 1) {
      int y = __shfl_up(x, (unsigned)d2, 64);
      if (lane >= d2) x += y;
    }
    if (lane == 63) wsum[wv] = x;
    __syncthreads();
    if (wv == 0 && lane < 16) {
      int w = wsum[lane];
      #pragma unroll
      for (int d2 = 1; d2 < 16; d2 <<= 1) {
        int y = __shfl_up(w, (unsigned)d2, 64);
        if (lane >= d2) w += y;
      }
      wsum[lane] = w;
    }
    __syncthreads();
    int tbase = x - sum + (wv ? wsum[wv - 1] : 0);
    int running = tbase;
    for (int i = 0; i < cntk; ++i) {
      off[base + i] = running;
      cur[base + i] = running;
      running += deg[base + i];
    }
    if (tid == 1023) off[n] = wsum[15];
    return;
  }
  if (b < 4) {
    // W fp32 [128][128] -> bf16 B-fragment order (2048 entries)
    int t = (b - 2) * 1024 + tid;
    if (t < 2048) {
      int lane = t & 63;
      int pair = t >> 6;  // ct*4 + kc
      int ct = pair >> 2, kc = pair & 3;
      int quad = lane >> 4, r = lane & 15;
      const float* src = W + (size_t)(kc * 32 + quad * 8) * 128 + ct * 16 + r;
      union { u16 v[8]; uint4 u; } pk;
      #pragma unroll
      for (int j = 0; j < 8; ++j) pk.v[j] = f2bf(src[(size_t)j * 128]);
      wfrag[t] = pk.u;
    }
    return;
  }
  // degree -> float norm = 1/sqrt(max(d,1))
  int i = (b - 4) * 1024 + tid;
  if (i < NCNT) {
    int d = cnt[i];
    float dv = (d < 1) ? 1.0f : (float)d;
    normf[i] = 1.0f / sqrtf(dv);
  }
}

// ---------------- fused transpose-in (ping-pong 2 tiles) + CSR scatter ----------------
// REVERTED to the round-2 structure: best measured variant (61.9 us). Round-3's
// wide-row contiguous-1KB loads were SLOWER (65.9) despite 0 bank conflicts --
// the ~2 TB/s cap is invariant to occupancy/MLP/segment size, so we keep the
// empirical best and stop mutating this kernel.
// Blocks [0, SB): scatter (4 edges/thread, atomic CSR fill).
// Blocks [SB, ...): TWO 64-node tiles (n0A, n0A+64) of one ac group, all 8
// loads issued up-front. Swizzle: phys(n,h) = n*128 + (((h>>2)+(n>>2))&31)*4 + (h&3).
__global__ __launch_bounds__(512) void k_tin_scatter(
    const float* __restrict__ in, const float* __restrict__ norm,
    u16* __restrict__ xp, int N, int SB,
    const int* __restrict__ e0s, const int* __restrict__ e0d,
    const int* __restrict__ e1s, const int* __restrict__ e1d,
    int E0, int E1,
    int* __restrict__ cur0, int* __restrict__ csr0,
    int* __restrict__ cur1, int* __restrict__ csr1) {
  __shared__ float tile[64 * 128];
  const int bid = blockIdx.x;
  const int tid = threadIdx.x;
  if (bid < SB) {
    #pragma unroll
    for (int k = 0; k < 4; ++k) {
      int i = (bid * 4 + k) * 512 + tid;
      if (i < E0) {
        int p = atomicAdd(&cur0[e0d[i]], 1);
        csr0[p] = e0s[i];
      } else {
        i -= E0;
        if (i < E1) {
          int p = atomicAdd(&cur1[e1d[i]], 1);
          csr1[p] = e1s[i];
        }
      }
    }
    return;
  }
  const int tb = bid - SB;
  const int n0A = (tb >> 2) << 7;  // pair of 64-node tiles
  const int ac = tb & 3;
  const int a = ac >> 1, c = ac & 1;
  const float* base = in + ((size_t)a * 256 + c) * (size_t)N;
  float4 vA[4], vB[4];
  // issue all 8 loads (A then B) before any LDS work
  #pragma unroll
  for (int i = 0; i < 4; ++i) {
    int fidx = (i << 9) + tid;
    int h = fidx >> 4;
    int t = fidx & 15;
    int gn = n0A + (t << 2);
    vA[i] = make_float4(0.f, 0.f, 0.f, 0.f);
    if (gn < N) vA[i] = *(const float4*)(base + (size_t)h * 2 * N + gn);
  }
  #pragma unroll
  for (int i = 0; i < 4; ++i) {
    int fidx = (i << 9) + tid;
    int h = fidx >> 4;
    int t = fidx & 15;
    int gn = n0A + 64 + (t << 2);
    vB[i] = make_float4(0.f, 0.f, 0.f, 0.f);
    if (gn < N) vB[i] = *(const float4*)(base + (size_t)h * 2 * N + gn);
  }
  // ---- tile A: LDS write, barrier, convert+store ----
  #pragma unroll
  for (int i = 0; i < 4; ++i) {
    int fidx = (i << 9) + tid;
    int h = fidx >> 4;
    int t = fidx & 15;
    int n = t << 2;
    int q = h >> 2, rem = h & 3;
    int rot = ((q + t) & 31) << 2;
    tile[(n + 0) * 128 + rot + rem] = vA[i].x;
    tile[(n + 1) * 128 + rot + rem] = vA[i].y;
    tile[(n + 2) * 128 + rot + rem] = vA[i].z;
    tile[(n + 3) * 128 + rot + rem] = vA[i].w;
  }
  __syncthreads();
  #pragma unroll
  for (int i = 0; i < 4; ++i) {
    int fidx = (i << 9) + tid;
    int h4 = fidx & 31;
    int n = fidx >> 5;
    int gn = n0A + n;
    if (gn < N) {
      float4 v = *(const float4*)(&tile[n * 128 + (((h4 + (n >> 2)) & 31) << 2)]);
      float s = norm[gn];
      ushort4 o;
      o.x = f2bf(v.x * s); o.y = f2bf(v.y * s);
      o.z = f2bf(v.z * s); o.w = f2bf(v.w * s);
      *(ushort4*)(xp + (size_t)gn * NF + ac * H128 + (h4 << 2)) = o;
    }
  }
  __syncthreads();
  // ---- tile B ----
  #pragma unroll
  for (int i = 0; i < 4; ++i) {
    int fidx = (i << 9) + tid;
    int h = fidx >> 4;
    int t = fidx & 15;
    int n = t << 2;
    int q = h >> 2, rem = h & 3;
    int rot = ((q + t) & 31) << 2;
    tile[(n + 0) * 128 + rot + rem] = vB[i].x;
    tile[(n + 1) * 128 + rot + rem] = vB[i].y;
    tile[(n + 2) * 128 + rot + rem] = vB[i].z;
    tile[(n + 3) * 128 + rot + rem] = vB[i].w;
  }
  __syncthreads();
  #pragma unroll
  for (int i = 0; i < 4; ++i) {
    int fidx = (i << 9) + tid;
    int h4 = fidx & 31;
    int n = fidx >> 5;
    int gn = n0A + 64 + n;
    if (gn < N) {
      float4 v = *(const float4*)(&tile[n * 128 + (((h4 + (n >> 2)) & 31) << 2)]);
      float s = norm[gn];
      ushort4 o;
      o.x = f2bf(v.x * s); o.y = f2bf(v.y * s);
      o.z = f2bf(v.z * s); o.w = f2bf(v.w * s);
      *(ushort4*)(xp + (size_t)gn * NF + ac * H128 + (h4 << 2)) = o;
    }
  }
}

// ---------------- fused aggregate + MFMA GEMM ----------------
// Block = 4 waves = 16 dst nodes. Wave w gathers nodes d0+w*4..+3 (full 512-feat
// row across 64 lanes, 16-deep unrolled gather: 16x16B loads in flight per
// lane before accumulation -- Poisson(16) degrees put most edges on the 16-path),
// scales by norm_dst, writes bf16 row to LDS atile. One barrier, then wave w
// computes the ac=w GEMM: out[16,128] = relu(A[16,128] @ W + b) (*scale).
// MODE 0: out bf16 [n][512], per-node scale (next layer's src norm).
// MODE 1: out fp32 written DIRECTLY transposed to [A,H,C,Nout] (final output).
template <int MODE>
__global__ __launch_bounds__(256) void k_agg_gemm(
    const u16* __restrict__ xp, const int* __restrict__ csr,
    const int* __restrict__ off, const float* __restrict__ norm_dst,
    const uint4* __restrict__ wfrag, const float* __restrict__ bias,
    const float* __restrict__ scale, void* __restrict__ outv, int Nout) {
  __shared__ uint4 wb[2048];      // 32 KB B-frags
  __shared__ u16 atile[16][520];  // 16.25 KB, rows 1040 B (16B aligned)
  const int tid = threadIdx.x;
  #pragma unroll
  for (int i = 0; i < 8; ++i) wb[i * 256 + tid] = wfrag[i * 256 + tid];
  const int wave = tid >> 6;
  const int lane = tid & 63;
  const int d0 = blockIdx.x << 4;
  // ---- gather phase ----
  const uint4* xpl = (const uint4*)xp + lane;  // lane's 16B slot; row stride 64 uint4
  #pragma unroll
  for (int i = 0; i < 4; ++i) {
    const int m = wave * 4 + i;
    const int d = d0 + m;
    const int s = off[d], e = off[d + 1];  // wave-uniform
    float acc[8];
    #pragma unroll
    for (int k = 0; k < 8; ++k) acc[k] = 0.f;
    int j = s;
    for (; j + 16 <= e; j += 16) {
      uint4 u[16];
      #pragma unroll
      for (int k = 0; k < 16; ++k) u[k] = xpl[(size_t)csr[j + k] * 64];
      #pragma unroll
      for (int k = 0; k < 16; ++k) addbf8(acc, u[k]);
    }
    for (; j + 8 <= e; j += 8) {
      uint4 u[8];
      #pragma unroll
      for (int k = 0; k < 8; ++k) u[k] = xpl[(size_t)csr[j + k] * 64];
      #pragma unroll
      for (int k = 0; k < 8; ++k) addbf8(acc, u[k]);
    }
    for (; j + 4 <= e; j += 4) {
      uint4 u[4];
      #pragma unroll
      for (int k = 0; k < 4; ++k) u[k] = xpl[(size_t)csr[j + k] * 64];
      #pragma unroll
      for (int k = 0; k < 4; ++k) addbf8(acc, u[k]);
    }
    for (; j < e; ++j) addbf8(acc, xpl[(size_t)csr[j] * 64]);
    float nd = norm_dst[d];
    union { u16 v[8]; uint4 u; } pk;
    #pragma unroll
    for (int k = 0; k < 8; ++k) pk.v[k] = f2bf(acc[k] * nd);
    *(uint4*)&atile[m][lane * 8] = pk.u;  // contiguous 1KB per wave
  }
  __syncthreads();
  // ---- GEMM phase: wave handles ac = wave ----
  const int quad = lane >> 4;
  const int r = lane & 15;
  short8 a[4];
  #pragma unroll
  for (int kc = 0; kc < 4; ++kc)
    a[kc] = *(const short8*)&atile[r][wave * 128 + kc * 32 + quad * 8];
  floatx4 acc[8];
  #pragma unroll
  for (int ct = 0; ct < 8; ++ct) acc[ct] = (floatx4){0.f, 0.f, 0.f, 0.f};
  #pragma unroll
  for (int kc = 0; kc < 4; ++kc) {
    #pragma unroll
    for (int ct = 0; ct < 8; ++ct) {
      short8 b = *(const short8*)&wb[(ct * 4 + kc) * 64 + lane];
      acc[ct] = __builtin_amdgcn_mfma_f32_16x16x32_bf16(a[kc], b, acc[ct], 0, 0, 0);
    }
  }
  // ---- epilogue: C/D row = quad*4+reg = node, col = ct*16+r = feature-within-ac ----
  if (MODE == 0) {
    float sc[4];
    #pragma unroll
    for (int reg = 0; reg < 4; ++reg) sc[reg] = scale[d0 + quad * 4 + reg];
    #pragma unroll
    for (int ct = 0; ct < 8; ++ct) {
      float bcol = bias[ct * 16 + r];
      #pragma unroll
      for (int reg = 0; reg < 4; ++reg) {
        float v = acc[ct][reg] + bcol;
        v = (v > 0.f ? v : 0.f) * sc[reg];
        ((u16*)outv)[(size_t)(d0 + quad * 4 + reg) * NF + wave * H128 + ct * 16 + r] = f2bf(v);
      }
    }
  } else {
    // out[a][h][c][n]: a=wave>>1, c=wave&1, h=ct*16+r, n=d0+quad*4+{0..3}
    const int aa = wave >> 1, cc = wave & 1;
    #pragma unroll
    for (int ct = 0; ct < 8; ++ct) {
      float bcol = bias[ct * 16 + r];
      float4 o;
      float v0 = acc[ct][0] + bcol; o.x = v0 > 0.f ? v0 : 0.f;
      float v1 = acc[ct][1] + bcol; o.y = v1 > 0.f ? v1 : 0.f;
      float v2 = acc[ct][2] + bcol; o.z = v2 > 0.f ? v2 : 0.f;
      float v3 = acc[ct][3] + bcol; o.w = v3 > 0.f ? v3 : 0.f;
      float* dst = (float*)outv +
          ((size_t)aa * 256 + (size_t)(ct * 16 + r) * 2 + cc) * (size_t)Nout +
          d0 + quad * 4;
      *(float4*)dst = o;
    }
  }
}

extern "C" void kernel_launch(void* const* d_in, const int* in_sizes, int n_in,
                              void* d_out, int out_size, void* d_ws, size_t ws_size,
                              hipStream_t stream) {
  const float* in_feat = (const float*)d_in[0];
  const float* W       = (const float*)d_in[1];
  const float* bias    = (const float*)d_in[2];
  const int* e0_src    = (const int*)d_in[3];
  const int* e0_dst    = (const int*)d_in[4];
  const int* e1_src    = (const int*)d_in[5];
  const int* e1_dst    = (const int*)d_in[6];
  const int N_DST0 = 20000;
  const int N_DST1 = 4096;
  const int N_SRC0 = in_sizes[0] / NF;  // 50000
  const int E0 = in_sizes[3];           // 320000
  const int E1 = in_sizes[5];           // 65536

  // ---- workspace layout (fully disjoint) ----
  u16* xp = (u16*)d_ws;                  // bf16 [N_SRC0][512] = 51.2 MB
  u16* h0 = xp + (size_t)N_SRC0 * NF;    // bf16 [N_DST0][512] = 20.5 MB
  int* ibase    = (int*)(h0 + (size_t)N_DST0 * NF);
  int* cnt_src0 = ibase;
  int* cnt_dst0 = cnt_src0 + N_SRC0;
  int* cnt_src1 = cnt_dst0 + N_DST0;
  int* cnt_dst1 = cnt_src1 + N_DST0;
  int* off0 = cnt_dst1 + N_DST1;
  int* cur0 = off0 + N_DST0 + 1;
  int* csr0 = cur0 + N_DST0;
  int* off1 = csr0 + E0;
  int* cur1 = off1 + N_DST1 + 1;
  int* csr1 = cur1 + N_DST1;
  uint4* wfrag = (uint4*)(((uintptr_t)(csr1 + E1) + 15) & ~(uintptr_t)15);  // 32 KB
  float* normf = (float*)(wfrag + 2048);  // float norms, mirrors cnt layout
  float* normf_src0 = normf;
  float* normf_dst0 = normf_src0 + N_SRC0;
  float* normf_src1 = normf_dst0 + N_DST0;
  float* normf_dst1 = normf_src1 + N_DST0;

  const int NCNT = N_SRC0 + N_DST0 + N_DST0 + N_DST1;
  hipMemsetAsync(cnt_src0, 0, (size_t)NCNT * sizeof(int), stream);

  // degree count (1 thread = both endpoints of 1 edge)
  k_count2<<<(E0 + E1 + 255) / 256, 256, 0, stream>>>(
      e0_src, e0_dst, e1_src, e1_dst, E0, E1, cnt_src0, cnt_dst0, cnt_src1, cnt_dst1);

  // fused scan (2 blocks) + wfrag pack (2 blocks) + norm (rest)
  k_prep<<<4 + (NCNT + 1023) / 1024, 1024, 0, stream>>>(
      cnt_src0, NCNT, normf,
      cnt_dst0, N_DST0, off0, cur0,
      cnt_dst1, N_DST1, off1, cur1,
      W, wfrag);

  // fused CSR scatter + ping-pong input transpose
  const int SB = (E0 + E1 + 2047) / 2048;            // 4 edges/thread
  const int ntiles = (N_SRC0 + 63) / 64;
  const int TB = ((ntiles + 1) / 2) * 4;             // 2 tiles per block x 4 ac
  k_tin_scatter<<<SB + TB, 512, 0, stream>>>(
      in_feat, normf_src0, xp, N_SRC0, SB,
      e0_src, e0_dst, e1_src, e1_dst, E0, E1,
      cur0, csr0, cur1, csr1);

  // layer 0: fused aggregate + GEMM -> bf16 h0 (folds layer-1 src norm)
  k_agg_gemm<0><<<N_DST0 / 16, 256, 0, stream>>>(
      xp, csr0, off0, normf_dst0, wfrag, bias, normf_src1, (void*)h0, 0);

  // layer 1: fused aggregate + GEMM -> fp32 written directly transposed to d_out
  k_agg_gemm<1><<<N_DST1 / 16, 256, 0, stream>>>(
      h0, csr1, off1, normf_dst1, wfrag, bias, nullptr, d_out, N_DST1);
}